// Round 5
// baseline (1167.431 us; speedup 1.0000x reference)
//
#include <hip/hip_runtime.h>

#define NMOD 6
#define BATCH 8192
#define EMB 300
#define DEPTH 6
#define NROWS 126  // 2+4+8+16+32+64

typedef __attribute__((ext_vector_type(4))) float f32x4;

// Orderable packing: monotone float->uint (handles sign), plus row index for
// first-occurrence tie-breaking under atomicMin (lower b wins ties).
__device__ __forceinline__ unsigned long long pack_key(double d, int b) {
    unsigned u = __float_as_uint((float)d);
    u = (u & 0x80000000u) ? ~u : (u | 0x80000000u);
    return ((unsigned long long)u << 32) | (unsigned)b;
}

// One wave per embedding row: fp64 L2-normalize; also init accumulators (last block).
__global__ void prep_kernel(const float* __restrict__ e0, const float* __restrict__ e1,
                            const float* __restrict__ e2, const float* __restrict__ e3,
                            const float* __restrict__ e4, const float* __restrict__ e5,
                            double* __restrict__ e_d, float* __restrict__ e_f,
                            unsigned long long* __restrict__ keys,
                            double* __restrict__ ec_sum, double* __restrict__ ce_sum) {
    const int bid = blockIdx.x;
    const int lane = threadIdx.x;
    if (bid >= NROWS) {
        for (int i = lane; i < NMOD * NROWS; i += 64) keys[i] = ~0ull;
        if (lane < NMOD * DEPTH) ec_sum[lane] = 0.0;
        if (lane == 0) ce_sum[0] = 0.0;
        return;
    }
    const float* src;
    if (bid < 2)       src = e0 + (size_t)bid * EMB;
    else if (bid < 6)  src = e1 + (size_t)(bid - 2) * EMB;
    else if (bid < 14) src = e2 + (size_t)(bid - 6) * EMB;
    else if (bid < 30) src = e3 + (size_t)(bid - 14) * EMB;
    else if (bid < 62) src = e4 + (size_t)(bid - 30) * EMB;
    else               src = e5 + (size_t)(bid - 62) * EMB;

    double w[5];
    double ss = 0.0;
    #pragma unroll
    for (int it = 0; it < 5; ++it) {
        int j = lane + it * 64;
        double v = (j < EMB) ? (double)src[j] : 0.0;
        w[it] = v;
        ss += v * v;
    }
    #pragma unroll
    for (int o = 32; o > 0; o >>= 1) ss += __shfl_xor(ss, o);
    double nrm = sqrt(ss);
    if (nrm < 1e-12) nrm = 1e-12;
    #pragma unroll
    for (int it = 0; it < 5; ++it) {
        int j = lane + it * 64;
        if (j < EMB) {
            double v = w[it] / nrm;
            e_d[(size_t)bid * EMB + j] = v;
            e_f[(size_t)bid * EMB + j] = (float)v;
        }
    }
}

// One wave per (modality, batch-row). 4 waves / 256-thread block; a block never
// crosses a modality boundary (8192 % 4 == 0).
__global__ __launch_bounds__(256) void route_kernel(
    const float* __restrict__ latents,
    const double* __restrict__ e_d, const float* __restrict__ e_f,
    float* __restrict__ tree_out, float* __restrict__ vec_out,
    unsigned long long* __restrict__ keys, double* __restrict__ ec_sum) {

    const int tid = threadIdx.x;
    const int w = tid >> 6;
    const int lane = tid & 63;
    const int row = blockIdx.x * 4 + w;           // 0..49151
    const int m = row >> 13;
    const int b = row & (BATCH - 1);

    const float* x = latents + (size_t)row * EMB;
    double r[5];
    double ss = 0.0;
    #pragma unroll
    for (int it = 0; it < 5; ++it) {
        int j = lane + it * 64;
        double v = (j < EMB) ? (double)x[j] : 0.0;
        r[it] = v;
        ss += v * v;
    }
    #pragma unroll
    for (int o = 32; o > 0; o >>= 1) ss += __shfl_xor(ss, o);
    double nrm = sqrt(ss);
    if (nrm < 1e-12) nrm = 1e-12;
    #pragma unroll
    for (int it = 0; it < 5; ++it) r[it] /= nrm;

    __shared__ double s_ec[4][DEPTH];

    int cur = 0;
    int idxs[DEPTH];
    #pragma unroll
    for (int l = 0; l < DEPTH; ++l) {
        const int base = (2 << l) - 2;            // 0,2,6,14,30,62
        const int c0 = 2 * cur;
        const size_t g0 = (size_t)(base + c0) * EMB;

        // Fast path: fp32 embedding table, fp64 accumulate (|err| <= ~1e-7).
        const float* p0 = e_f + g0;
        const float* p1 = p0 + EMB;
        double s0 = 0.0, s1 = 0.0;
        #pragma unroll
        for (int it = 0; it < 5; ++it) {
            int j = lane + it * 64;
            if (j < EMB) {
                double rv = r[it];
                s0 += rv * (double)p0[j];
                s1 += rv * (double)p1[j];
            }
        }
        #pragma unroll
        for (int o = 32; o > 0; o >>= 1) { s0 += __shfl_xor(s0, o); s1 += __shfl_xor(s1, o); }

        // Escalate near-ties to the exact fp64 table (wave-uniform branch, rare).
        if (fabs(s0 - s1) < 1e-3) {
            const double* q0 = e_d + g0;
            const double* q1 = q0 + EMB;
            s0 = 0.0; s1 = 0.0;
            #pragma unroll
            for (int it = 0; it < 5; ++it) {
                int j = lane + it * 64;
                if (j < EMB) {
                    double rv = r[it];
                    s0 += rv * q0[j];
                    s1 += rv * q1[j];
                }
            }
            #pragma unroll
            for (int o = 32; o > 0; o >>= 1) { s0 += __shfl_xor(s0, o); s1 += __shfl_xor(s1, o); }
        }

        double d0 = 1.0 - s0, d1 = 1.0 - s1;
        int sel = (d1 < d0) ? 1 : 0;              // tie -> first occurrence (c0)
        int idx = c0 + sel;
        idxs[l] = idx;
        if (lane == 0) {
            s_ec[w][l] = sel ? d1 : d0;
            // Guarded atomics: only issue if we'd improve the current min.
            // keys decrease monotonically, so a stale read only over-issues.
            unsigned long long k0 = pack_key(d0, b);
            unsigned long long k1 = pack_key(d1, b);
            unsigned long long* a0 = &keys[m * NROWS + base + c0];
            if (k0 < *a0) atomicMin(a0, k0);
            if (k1 < a0[1]) atomicMin(a0 + 1, k1);
        }
        cur = idx;
    }

    // tree output: static indices only (runtime-indexed local arrays spill to scratch).
    #pragma unroll
    for (int l = 0; l < DEPTH; ++l) {
        if (lane == l) {
            __builtin_nontemporal_store((float)idxs[l], &tree_out[(size_t)row * DEPTH + l]);
        }
    }

    // vec output: copy selected normalized embedding rows, float4 coalesced,
    // nontemporal (write-once stream; keep e_f hot in L2).
    #pragma unroll
    for (int l = 0; l < DEPTH; ++l) {
        const int base = (2 << l) - 2;
        const f32x4* src = (const f32x4*)(e_f + (size_t)(base + idxs[l]) * EMB);
        f32x4* dst = (f32x4*)(vec_out + ((size_t)row * DEPTH + l) * EMB);
        for (int i = lane; i < EMB / 4; i += 64) {
            __builtin_nontemporal_store(src[i], &dst[i]);
        }
    }

    __syncthreads();
    if (tid < DEPTH) {
        double s = s_ec[0][tid] + s_ec[1][tid] + s_ec[2][tid] + s_ec[3][tid];
        atomicAdd(&ec_sum[m * DEPTH + tid], s);
    }
}

// One wave per (modality, tree-node) cell: recompute 1 - cos(x[b2], e_k) exactly.
__global__ void ce_kernel(const float* __restrict__ latents,
                          const double* __restrict__ e_d,
                          const unsigned long long* __restrict__ keys,
                          double* __restrict__ ce_sum) {
    const int tid = threadIdx.x;
    const int w = tid >> 6;
    const int lane = tid & 63;
    const int c = blockIdx.x * 4 + w;
    if (c >= NMOD * NROWS) return;
    const int m = c / NROWS;
    const int g = c % NROWS;
    int K;
    if (g < 2) K = 2;
    else if (g < 6) K = 4;
    else if (g < 14) K = 8;
    else if (g < 30) K = 16;
    else if (g < 62) K = 32;
    else K = 64;

    unsigned long long key = keys[c];
    int b2 = (key == ~0ull) ? 0 : (int)(key & 0xFFFFFFFFull);  // all-inf column -> argmin = 0

    const float* x = latents + ((size_t)m * BATCH + b2) * EMB;
    const double* e = e_d + (size_t)g * EMB;
    double ss = 0.0, dot = 0.0;
    #pragma unroll
    for (int it = 0; it < 5; ++it) {
        int j = lane + it * 64;
        if (j < EMB) {
            double v = (double)x[j];
            ss += v * v;
            dot += v * e[j];
        }
    }
    #pragma unroll
    for (int o = 32; o > 0; o >>= 1) { ss += __shfl_xor(ss, o); dot += __shfl_xor(dot, o); }
    double nx = sqrt(ss);
    if (nx < 1e-8) nx = 1e-8;
    double dd = 1.0 - dot / nx;                   // ||e|| == 1
    if (lane == 0) atomicAdd(ce_sum, 2.0 * dd / (36.0 * (double)K));
}

__global__ void final_kernel(const double* __restrict__ ec_sum,
                             const double* __restrict__ ce_sum,
                             float* __restrict__ loss_out) {
    const int lane = threadIdx.x;
    double s = (lane < NMOD * DEPTH) ? ec_sum[lane] : 0.0;
    #pragma unroll
    for (int o = 32; o > 0; o >>= 1) s += __shfl_xor(s, o);
    if (lane == 0) loss_out[0] = (float)(s * 2.0 / (36.0 * (double)BATCH) + ce_sum[0]);
}

extern "C" void kernel_launch(void* const* d_in, const int* in_sizes, int n_in,
                              void* d_out, int out_size, void* d_ws, size_t ws_size,
                              hipStream_t stream) {
    const float* latents = (const float*)d_in[0];
    const float* e0 = (const float*)d_in[1];
    const float* e1 = (const float*)d_in[2];
    const float* e2 = (const float*)d_in[3];
    const float* e3 = (const float*)d_in[4];
    const float* e4 = (const float*)d_in[5];
    const float* e5 = (const float*)d_in[6];

    float* out = (float*)d_out;
    float* tree_out = out;                                            // (6,8192,6)
    float* vec_out = out + (size_t)NMOD * BATCH * DEPTH;              // (6,8192,6,300)
    float* loss_out = vec_out + (size_t)NMOD * BATCH * DEPTH * EMB;   // scalar

    char* ws = (char*)d_ws;
    double* e_d = (double*)ws;                                  // 126*300*8 = 302400 B
    float* e_f = (float*)(ws + 302400);                         // 126*300*4 = 151200 B
    unsigned long long* keys = (unsigned long long*)(ws + 453600);  // 756*8 = 6048 B
    double* ec_sum = (double*)(ws + 459648);                    // 36*8 = 288 B
    double* ce_sum = (double*)(ws + 459936);                    // 8 B

    prep_kernel<<<dim3(NROWS + 1), dim3(64), 0, stream>>>(
        e0, e1, e2, e3, e4, e5, e_d, e_f, keys, ec_sum, ce_sum);
    route_kernel<<<dim3(NMOD * BATCH / 4), dim3(256), 0, stream>>>(
        latents, e_d, e_f, tree_out, vec_out, keys, ec_sum);
    ce_kernel<<<dim3((NMOD * NROWS + 3) / 4), dim3(256), 0, stream>>>(
        latents, e_d, keys, ce_sum);
    final_kernel<<<dim3(1), dim3(64), 0, stream>>>(ec_sum, ce_sum, loss_out);
}

// Round 6
// 463.715 us; speedup vs baseline: 2.5176x; 2.5176x over previous
//
#include <hip/hip_runtime.h>

#define NMOD 6
#define BATCH 8192
#define EMB 300
#define DEPTH 6
#define NROWS 126   // 2+4+8+16+32+64
#define NPART 32    // argmin partition count (contention cap: 2048/NPART = 64)

typedef __attribute__((ext_vector_type(4))) float f32x4;

// Orderable packing: monotone float->uint (handles sign), plus row index for
// first-occurrence tie-breaking under min (lower b wins ties).
__device__ __forceinline__ unsigned long long pack_key(double d, int b) {
    unsigned u = __float_as_uint((float)d);
    u = (u & 0x80000000u) ? ~u : (u | 0x80000000u);
    return ((unsigned long long)u << 32) | (unsigned)b;
}

// One wave per embedding row: fp64 L2-normalize; last block inits kpart.
__global__ void prep_kernel(const float* __restrict__ e0, const float* __restrict__ e1,
                            const float* __restrict__ e2, const float* __restrict__ e3,
                            const float* __restrict__ e4, const float* __restrict__ e5,
                            double* __restrict__ e_d, float* __restrict__ e_f,
                            unsigned long long* __restrict__ kpart) {
    const int bid = blockIdx.x;
    const int lane = threadIdx.x;
    if (bid >= NROWS) {
        for (int i = lane; i < NPART * NMOD * NROWS; i += 64) kpart[i] = ~0ull;
        return;
    }
    const float* src;
    if (bid < 2)       src = e0 + (size_t)bid * EMB;
    else if (bid < 6)  src = e1 + (size_t)(bid - 2) * EMB;
    else if (bid < 14) src = e2 + (size_t)(bid - 6) * EMB;
    else if (bid < 30) src = e3 + (size_t)(bid - 14) * EMB;
    else if (bid < 62) src = e4 + (size_t)(bid - 30) * EMB;
    else               src = e5 + (size_t)(bid - 62) * EMB;

    double w[5];
    double ss = 0.0;
    #pragma unroll
    for (int it = 0; it < 5; ++it) {
        int j = lane + it * 64;
        double v = (j < EMB) ? (double)src[j] : 0.0;
        w[it] = v;
        ss += v * v;
    }
    #pragma unroll
    for (int o = 32; o > 0; o >>= 1) ss += __shfl_xor(ss, o);
    double nrm = sqrt(ss);
    if (nrm < 1e-12) nrm = 1e-12;
    #pragma unroll
    for (int it = 0; it < 5; ++it) {
        int j = lane + it * 64;
        if (j < EMB) {
            double v = w[it] / nrm;
            e_d[(size_t)bid * EMB + j] = v;
            e_f[(size_t)bid * EMB + j] = (float)v;
        }
    }
}

// One wave per (modality, batch-row). 4 waves / 256-thread block.
// NO contended global atomics: block-local LDS argmin table, partitioned export.
__global__ __launch_bounds__(256) void route_kernel(
    const float* __restrict__ latents,
    const double* __restrict__ e_d, const float* __restrict__ e_f,
    float* __restrict__ tree_out, float* __restrict__ vec_out,
    unsigned long long* __restrict__ kpart, double* __restrict__ ecp) {

    __shared__ unsigned long long tbl[NROWS];
    __shared__ double s_ec[4][DEPTH];

    const int tid = threadIdx.x;
    for (int i = tid; i < NROWS; i += 256) tbl[i] = ~0ull;
    __syncthreads();

    const int w = tid >> 6;
    const int lane = tid & 63;
    const int row = blockIdx.x * 4 + w;           // 0..49151
    const int m = row >> 13;
    const int b = row & (BATCH - 1);

    const float* x = latents + (size_t)row * EMB;
    double r[5];
    double ss = 0.0;
    #pragma unroll
    for (int it = 0; it < 5; ++it) {
        int j = lane + it * 64;
        double v = (j < EMB) ? (double)x[j] : 0.0;
        r[it] = v;
        ss += v * v;
    }
    #pragma unroll
    for (int o = 32; o > 0; o >>= 1) ss += __shfl_xor(ss, o);
    double nrm = sqrt(ss);
    if (nrm < 1e-12) nrm = 1e-12;
    #pragma unroll
    for (int it = 0; it < 5; ++it) r[it] /= nrm;

    int cur = 0;
    int idxs[DEPTH];
    #pragma unroll
    for (int l = 0; l < DEPTH; ++l) {
        const int base = (2 << l) - 2;            // 0,2,6,14,30,62
        const int c0 = 2 * cur;
        const size_t g0 = (size_t)(base + c0) * EMB;

        // Fast path: fp32 embedding table, fp64 accumulate (|err| <= ~1e-7).
        const float* p0 = e_f + g0;
        const float* p1 = p0 + EMB;
        double s0 = 0.0, s1 = 0.0;
        #pragma unroll
        for (int it = 0; it < 5; ++it) {
            int j = lane + it * 64;
            if (j < EMB) {
                double rv = r[it];
                s0 += rv * (double)p0[j];
                s1 += rv * (double)p1[j];
            }
        }
        #pragma unroll
        for (int o = 32; o > 0; o >>= 1) { s0 += __shfl_xor(s0, o); s1 += __shfl_xor(s1, o); }

        // Escalate near-ties to the exact fp64 table (wave-uniform branch, rare).
        if (fabs(s0 - s1) < 1e-3) {
            const double* q0 = e_d + g0;
            const double* q1 = q0 + EMB;
            s0 = 0.0; s1 = 0.0;
            #pragma unroll
            for (int it = 0; it < 5; ++it) {
                int j = lane + it * 64;
                if (j < EMB) {
                    double rv = r[it];
                    s0 += rv * q0[j];
                    s1 += rv * q1[j];
                }
            }
            #pragma unroll
            for (int o = 32; o > 0; o >>= 1) { s0 += __shfl_xor(s0, o); s1 += __shfl_xor(s1, o); }
        }

        double d0 = 1.0 - s0, d1 = 1.0 - s1;
        int sel = (d1 < d0) ? 1 : 0;              // tie -> first occurrence (c0)
        int idx = c0 + sel;
        idxs[l] = idx;
        if (lane == 0) {
            s_ec[w][l] = sel ? d1 : d0;
            atomicMin(&tbl[base + c0],     pack_key(d0, b));   // LDS atomics: cheap
            atomicMin(&tbl[base + c0 + 1], pack_key(d1, b));
        }
        cur = idx;
    }

    // tree output: static indices only (runtime-indexed local arrays spill to scratch).
    #pragma unroll
    for (int l = 0; l < DEPTH; ++l) {
        if (lane == l) {
            __builtin_nontemporal_store((float)idxs[l], &tree_out[(size_t)row * DEPTH + l]);
        }
    }

    // vec output: copy selected normalized embedding rows, float4 coalesced,
    // nontemporal (write-once stream; keep e_f hot in L2).
    #pragma unroll
    for (int l = 0; l < DEPTH; ++l) {
        const int base = (2 << l) - 2;
        const f32x4* src = (const f32x4*)(e_f + (size_t)(base + idxs[l]) * EMB);
        f32x4* dst = (f32x4*)(vec_out + ((size_t)row * DEPTH + l) * EMB);
        for (int i = lane; i < EMB / 4; i += 64) {
            __builtin_nontemporal_store(src[i], &dst[i]);
        }
    }

    __syncthreads();

    // ec partials: plain store per (block, level) — no global atomics.
    const int bm = blockIdx.x & 2047;             // block index within modality
    if (tid < DEPTH) {
        double s = s_ec[0][tid] + s_ec[1][tid] + s_ec[2][tid] + s_ec[3][tid];
        ecp[((size_t)m * DEPTH + tid) * 2048 + bm] = s;
    }

    // Export block argmin table into partitioned global table.
    // Contention per (partition, cell) <= 2048/NPART = 64.
    const int part = blockIdx.x & (NPART - 1);
    for (int i = tid; i < NROWS; i += 256) {
        unsigned long long v = tbl[i];
        if (v != ~0ull) atomicMin(&kpart[(size_t)part * (NMOD * NROWS) + m * NROWS + i], v);
    }
}

// Fold the NPART partitions into final keys (plain stores, no atomics).
__global__ void kreduce_kernel(const unsigned long long* __restrict__ kpart,
                               unsigned long long* __restrict__ keys) {
    const int c = blockIdx.x * 256 + threadIdx.x;
    if (c >= NMOD * NROWS) return;
    unsigned long long v = ~0ull;
    #pragma unroll 4
    for (int p = 0; p < NPART; ++p) {
        unsigned long long u = kpart[(size_t)p * (NMOD * NROWS) + c];
        if (u < v) v = u;
    }
    keys[c] = v;
}

// Sum 2048 block-partials per (modality, level).
__global__ __launch_bounds__(256) void ec_reduce_kernel(const double* __restrict__ ecp,
                                                        double* __restrict__ ec_sum) {
    const int tid = threadIdx.x;
    double s = 0.0;
    for (int i = tid; i < 2048; i += 256) s += ecp[(size_t)blockIdx.x * 2048 + i];
    #pragma unroll
    for (int o = 32; o > 0; o >>= 1) s += __shfl_xor(s, o);
    __shared__ double sw[4];
    if ((tid & 63) == 0) sw[tid >> 6] = s;
    __syncthreads();
    if (tid == 0) ec_sum[blockIdx.x] = sw[0] + sw[1] + sw[2] + sw[3];
}

// One wave per (modality, tree-node) cell: recompute 1 - cos(x[b2], e_k) exactly.
__global__ void ce_kernel(const float* __restrict__ latents,
                          const double* __restrict__ e_d,
                          const unsigned long long* __restrict__ keys,
                          double* __restrict__ cev) {
    const int tid = threadIdx.x;
    const int w = tid >> 6;
    const int lane = tid & 63;
    const int c = blockIdx.x * 4 + w;
    if (c >= NMOD * NROWS) return;
    const int m = c / NROWS;
    const int g = c % NROWS;
    int K;
    if (g < 2) K = 2;
    else if (g < 6) K = 4;
    else if (g < 14) K = 8;
    else if (g < 30) K = 16;
    else if (g < 62) K = 32;
    else K = 64;

    unsigned long long key = keys[c];
    int b2 = (key == ~0ull) ? 0 : (int)(key & 0xFFFFFFFFull);  // all-inf column -> argmin = 0

    const float* x = latents + ((size_t)m * BATCH + b2) * EMB;
    const double* e = e_d + (size_t)g * EMB;
    double ss = 0.0, dot = 0.0;
    #pragma unroll
    for (int it = 0; it < 5; ++it) {
        int j = lane + it * 64;
        if (j < EMB) {
            double v = (double)x[j];
            ss += v * v;
            dot += v * e[j];
        }
    }
    #pragma unroll
    for (int o = 32; o > 0; o >>= 1) { ss += __shfl_xor(ss, o); dot += __shfl_xor(dot, o); }
    double nx = sqrt(ss);
    if (nx < 1e-8) nx = 1e-8;
    double dd = 1.0 - dot / nx;                   // ||e|| == 1
    if (lane == 0) cev[c] = 2.0 * dd / (36.0 * (double)K);
}

__global__ __launch_bounds__(256) void final_kernel(const double* __restrict__ ec_sum,
                                                    const double* __restrict__ cev,
                                                    float* __restrict__ loss_out) {
    const int tid = threadIdx.x;
    double s = 0.0;
    for (int i = tid; i < NMOD * NROWS; i += 256) s += cev[i];
    for (int i = tid; i < NMOD * DEPTH; i += 256) s += ec_sum[i] * (2.0 / (36.0 * (double)BATCH));
    #pragma unroll
    for (int o = 32; o > 0; o >>= 1) s += __shfl_xor(s, o);
    __shared__ double sw[4];
    if ((tid & 63) == 0) sw[tid >> 6] = s;
    __syncthreads();
    if (tid == 0) loss_out[0] = (float)(sw[0] + sw[1] + sw[2] + sw[3]);
}

extern "C" void kernel_launch(void* const* d_in, const int* in_sizes, int n_in,
                              void* d_out, int out_size, void* d_ws, size_t ws_size,
                              hipStream_t stream) {
    const float* latents = (const float*)d_in[0];
    const float* e0 = (const float*)d_in[1];
    const float* e1 = (const float*)d_in[2];
    const float* e2 = (const float*)d_in[3];
    const float* e3 = (const float*)d_in[4];
    const float* e4 = (const float*)d_in[5];
    const float* e5 = (const float*)d_in[6];

    float* out = (float*)d_out;
    float* tree_out = out;                                            // (6,8192,6)
    float* vec_out = out + (size_t)NMOD * BATCH * DEPTH;              // (6,8192,6,300)
    float* loss_out = vec_out + (size_t)NMOD * BATCH * DEPTH * EMB;   // scalar

    char* ws = (char*)d_ws;
    double* e_d = (double*)ws;                                        // 302400 B
    float* e_f = (float*)(ws + 302400);                               // 151200 B -> 453600
    unsigned long long* keys = (unsigned long long*)(ws + 453600);    // 6048 -> 459648
    unsigned long long* kpart = (unsigned long long*)(ws + 459648);   // 32*756*8 = 193536 -> 653184
    double* ecp = (double*)(ws + 653184);                             // 36*2048*8 = 589824 -> 1243008
    double* cev = (double*)(ws + 1243008);                            // 6048 -> 1249056
    double* ec_sum = (double*)(ws + 1249056);                         // 288 -> 1249344

    prep_kernel<<<dim3(NROWS + 1), dim3(64), 0, stream>>>(
        e0, e1, e2, e3, e4, e5, e_d, e_f, kpart);
    route_kernel<<<dim3(NMOD * BATCH / 4), dim3(256), 0, stream>>>(
        latents, e_d, e_f, tree_out, vec_out, kpart, ecp);
    kreduce_kernel<<<dim3((NMOD * NROWS + 255) / 256), dim3(256), 0, stream>>>(kpart, keys);
    ec_reduce_kernel<<<dim3(NMOD * DEPTH), dim3(256), 0, stream>>>(ecp, ec_sum);
    ce_kernel<<<dim3((NMOD * NROWS + 3) / 4), dim3(256), 0, stream>>>(
        latents, e_d, keys, cev);
    final_kernel<<<dim3(1), dim3(256), 0, stream>>>(ec_sum, cev, loss_out);
}

// Round 7
// 462.078 us; speedup vs baseline: 2.5265x; 1.0035x over previous
//
#include <hip/hip_runtime.h>

#define NMOD 6
#define BATCH 8192
#define EMB 300
#define DEPTH 6
#define NROWS 126   // 2+4+8+16+32+64
#define NPART 32    // argmin partition count (contention cap: 2048/NPART = 64)

typedef __attribute__((ext_vector_type(4))) float f32x4;

// Orderable packing: monotone float->uint (handles sign), plus row index for
// first-occurrence tie-breaking under min (lower b wins ties).
__device__ __forceinline__ unsigned long long pack_key(float d, int b) {
    unsigned u = __float_as_uint(d);
    u = (u & 0x80000000u) ? ~u : (u | 0x80000000u);
    return ((unsigned long long)u << 32) | (unsigned)b;
}

// One wave per embedding row: fp64 L2-normalize; last block inits kpart.
__global__ void prep_kernel(const float* __restrict__ e0, const float* __restrict__ e1,
                            const float* __restrict__ e2, const float* __restrict__ e3,
                            const float* __restrict__ e4, const float* __restrict__ e5,
                            double* __restrict__ e_d, float* __restrict__ e_f,
                            unsigned long long* __restrict__ kpart) {
    const int bid = blockIdx.x;
    const int lane = threadIdx.x;
    if (bid >= NROWS) {
        for (int i = lane; i < NPART * NMOD * NROWS; i += 64) kpart[i] = ~0ull;
        return;
    }
    const float* src;
    if (bid < 2)       src = e0 + (size_t)bid * EMB;
    else if (bid < 6)  src = e1 + (size_t)(bid - 2) * EMB;
    else if (bid < 14) src = e2 + (size_t)(bid - 6) * EMB;
    else if (bid < 30) src = e3 + (size_t)(bid - 14) * EMB;
    else if (bid < 62) src = e4 + (size_t)(bid - 30) * EMB;
    else               src = e5 + (size_t)(bid - 62) * EMB;

    double w[5];
    double ss = 0.0;
    #pragma unroll
    for (int it = 0; it < 5; ++it) {
        int j = lane + it * 64;
        double v = (j < EMB) ? (double)src[j] : 0.0;
        w[it] = v;
        ss += v * v;
    }
    #pragma unroll
    for (int o = 32; o > 0; o >>= 1) ss += __shfl_xor(ss, o);
    double nrm = sqrt(ss);
    if (nrm < 1e-12) nrm = 1e-12;
    #pragma unroll
    for (int it = 0; it < 5; ++it) {
        int j = lane + it * 64;
        if (j < EMB) {
            double v = w[it] / nrm;
            e_d[(size_t)bid * EMB + j] = v;
            e_f[(size_t)bid * EMB + j] = (float)v;
        }
    }
}

// One wave per (modality, batch-row). 4 waves / 256-thread block.
// fp32 fast path (norm factor cancels in the comparison; dot error ~1e-6 vs
// 1e-3 escalation threshold); rare near-ties escalate to exact fp64.
__global__ __launch_bounds__(256) void route_kernel(
    const float* __restrict__ latents,
    const double* __restrict__ e_d, const float* __restrict__ e_f,
    float* __restrict__ tree_out, float* __restrict__ vec_out,
    unsigned long long* __restrict__ kpart, double* __restrict__ ecp) {

    __shared__ unsigned long long tbl[NROWS];
    __shared__ double s_ec[4][DEPTH];

    const int tid = threadIdx.x;
    for (int i = tid; i < NROWS; i += 256) tbl[i] = ~0ull;
    __syncthreads();

    const int w = tid >> 6;
    const int lane = tid & 63;
    const int row = blockIdx.x * 4 + w;           // 0..49151
    const int m = row >> 13;
    const int b = row & (BATCH - 1);

    // x in registers, float4 layout: lane holds elems [4*lane..4*lane+3] and
    // (lane<11) [256+4*lane .. 256+4*lane+3]. 300 = 75 float4 exactly.
    const f32x4* x4 = (const f32x4*)(latents + (size_t)row * EMB);
    const f32x4 zero4 = {0.f, 0.f, 0.f, 0.f};
    f32x4 xu0 = x4[lane];
    f32x4 xu1 = (lane < 11) ? x4[64 + lane] : zero4;

    float ssf = xu0[0]*xu0[0] + xu0[1]*xu0[1] + xu0[2]*xu0[2] + xu0[3]*xu0[3]
              + xu1[0]*xu1[0] + xu1[1]*xu1[1] + xu1[2]*xu1[2] + xu1[3]*xu1[3];
    #pragma unroll
    for (int o = 32; o > 0; o >>= 1) ssf += __shfl_xor(ssf, o);
    const float rinv = 1.0f / fmaxf(sqrtf(ssf), 1e-12f);

    int cur = 0;
    int idxs[DEPTH];
    #pragma unroll
    for (int l = 0; l < DEPTH; ++l) {
        const int base = (2 << l) - 2;            // 0,2,6,14,30,62
        const int c0 = 2 * cur;
        const size_t g0 = (size_t)(base + c0) * EMB;

        const f32x4* p04 = (const f32x4*)(e_f + g0);
        const f32x4* p14 = (const f32x4*)(e_f + g0 + EMB);
        f32x4 a0 = p04[lane];
        f32x4 b0 = p14[lane];
        f32x4 a1 = zero4, b1 = zero4;
        if (lane < 11) { a1 = p04[64 + lane]; b1 = p14[64 + lane]; }

        float t0 = xu0[0]*a0[0] + xu0[1]*a0[1] + xu0[2]*a0[2] + xu0[3]*a0[3]
                 + xu1[0]*a1[0] + xu1[1]*a1[1] + xu1[2]*a1[2] + xu1[3]*a1[3];
        float t1 = xu0[0]*b0[0] + xu0[1]*b0[1] + xu0[2]*b0[2] + xu0[3]*b0[3]
                 + xu1[0]*b1[0] + xu1[1]*b1[1] + xu1[2]*b1[2] + xu1[3]*b1[3];
        #pragma unroll
        for (int o = 32; o > 0; o >>= 1) { t0 += __shfl_xor(t0, o); t1 += __shfl_xor(t1, o); }
        float s0 = t0 * rinv, s1 = t1 * rinv;

        double d0x, d1x;
        bool esc = fabsf(s0 - s1) < 1e-3f;        // wave-uniform (post-reduce)
        if (esc) {
            // Exact fp64 recompute from pristine fp32 x registers.
            const double* q0 = e_d + g0;
            const double* q1 = q0 + EMB;
            double ssd = 0.0, u0 = 0.0, u1 = 0.0;
            #pragma unroll
            for (int q = 0; q < 4; ++q) {
                double xv = (double)xu0[q];
                ssd += xv * xv;
                u0 += xv * q0[4 * lane + q];
                u1 += xv * q1[4 * lane + q];
            }
            if (lane < 11) {
                #pragma unroll
                for (int q = 0; q < 4; ++q) {
                    double xv = (double)xu1[q];
                    ssd += xv * xv;
                    u0 += xv * q0[256 + 4 * lane + q];
                    u1 += xv * q1[256 + 4 * lane + q];
                }
            }
            #pragma unroll
            for (int o = 32; o > 0; o >>= 1) {
                ssd += __shfl_xor(ssd, o);
                u0 += __shfl_xor(u0, o);
                u1 += __shfl_xor(u1, o);
            }
            double nd = sqrt(ssd);
            if (nd < 1e-12) nd = 1e-12;
            d0x = 1.0 - u0 / nd;
            d1x = 1.0 - u1 / nd;
        } else {
            d0x = (double)(1.0f - s0);
            d1x = (double)(1.0f - s1);
        }

        int sel = (d1x < d0x) ? 1 : 0;            // tie -> first occurrence (c0)
        int idx = c0 + sel;
        idxs[l] = idx;
        if (lane == 0) {
            s_ec[w][l] = sel ? d1x : d0x;
            atomicMin(&tbl[base + c0],     pack_key((float)d0x, b));  // LDS atomics
            atomicMin(&tbl[base + c0 + 1], pack_key((float)d1x, b));
        }
        cur = idx;
    }

    // tree output: static indices only (runtime-indexed local arrays spill to scratch).
    #pragma unroll
    for (int l = 0; l < DEPTH; ++l) {
        if (lane == l) {
            __builtin_nontemporal_store((float)idxs[l], &tree_out[(size_t)row * DEPTH + l]);
        }
    }

    // vec output: copy selected normalized embedding rows, float4 coalesced,
    // nontemporal (write-once stream; keep e_f hot in L2).
    #pragma unroll
    for (int l = 0; l < DEPTH; ++l) {
        const int base = (2 << l) - 2;
        const f32x4* src = (const f32x4*)(e_f + (size_t)(base + idxs[l]) * EMB);
        f32x4* dst = (f32x4*)(vec_out + ((size_t)row * DEPTH + l) * EMB);
        for (int i = lane; i < EMB / 4; i += 64) {
            __builtin_nontemporal_store(src[i], &dst[i]);
        }
    }

    __syncthreads();

    // ec partials: plain store per (block, level) — no global atomics.
    const int bm = blockIdx.x & 2047;             // block index within modality
    if (tid < DEPTH) {
        double s = s_ec[0][tid] + s_ec[1][tid] + s_ec[2][tid] + s_ec[3][tid];
        ecp[((size_t)m * DEPTH + tid) * 2048 + bm] = s;
    }

    // Export block argmin table into partitioned global table.
    // Contention per (partition, cell) <= 2048/NPART = 64.
    const int part = blockIdx.x & (NPART - 1);
    for (int i = tid; i < NROWS; i += 256) {
        unsigned long long v = tbl[i];
        if (v != ~0ull) atomicMin(&kpart[(size_t)part * (NMOD * NROWS) + m * NROWS + i], v);
    }
}

// Merged reduction: blocks 0..35 sum ec partials; blocks 36..38 fold kpart->keys.
__global__ __launch_bounds__(256) void reduce_kernel(
    const unsigned long long* __restrict__ kpart, unsigned long long* __restrict__ keys,
    const double* __restrict__ ecp, double* __restrict__ ec_sum) {
    const int bid = blockIdx.x;
    const int tid = threadIdx.x;
    if (bid < NMOD * DEPTH) {
        double s = 0.0;
        for (int i = tid; i < 2048; i += 256) s += ecp[(size_t)bid * 2048 + i];
        #pragma unroll
        for (int o = 32; o > 0; o >>= 1) s += __shfl_xor(s, o);
        __shared__ double sw[4];
        if ((tid & 63) == 0) sw[tid >> 6] = s;
        __syncthreads();
        if (tid == 0) ec_sum[bid] = sw[0] + sw[1] + sw[2] + sw[3];
    } else {
        const int c = (bid - NMOD * DEPTH) * 256 + tid;
        if (c < NMOD * NROWS) {
            unsigned long long v = ~0ull;
            #pragma unroll 4
            for (int p = 0; p < NPART; ++p) {
                unsigned long long u = kpart[(size_t)p * (NMOD * NROWS) + c];
                if (u < v) v = u;
            }
            keys[c] = v;
        }
    }
}

// One wave per (modality, tree-node) cell: recompute 1 - cos(x[b2], e_k) exactly.
__global__ void ce_kernel(const float* __restrict__ latents,
                          const double* __restrict__ e_d,
                          const unsigned long long* __restrict__ keys,
                          double* __restrict__ cev) {
    const int tid = threadIdx.x;
    const int w = tid >> 6;
    const int lane = tid & 63;
    const int c = blockIdx.x * 4 + w;
    if (c >= NMOD * NROWS) return;
    const int m = c / NROWS;
    const int g = c % NROWS;
    int K;
    if (g < 2) K = 2;
    else if (g < 6) K = 4;
    else if (g < 14) K = 8;
    else if (g < 30) K = 16;
    else if (g < 62) K = 32;
    else K = 64;

    unsigned long long key = keys[c];
    int b2 = (key == ~0ull) ? 0 : (int)(key & 0xFFFFFFFFull);  // all-inf column -> argmin = 0

    const float* x = latents + ((size_t)m * BATCH + b2) * EMB;
    const double* e = e_d + (size_t)g * EMB;
    double ss = 0.0, dot = 0.0;
    #pragma unroll
    for (int it = 0; it < 5; ++it) {
        int j = lane + it * 64;
        if (j < EMB) {
            double v = (double)x[j];
            ss += v * v;
            dot += v * e[j];
        }
    }
    #pragma unroll
    for (int o = 32; o > 0; o >>= 1) { ss += __shfl_xor(ss, o); dot += __shfl_xor(dot, o); }
    double nx = sqrt(ss);
    if (nx < 1e-8) nx = 1e-8;
    double dd = 1.0 - dot / nx;                   // ||e|| == 1
    if (lane == 0) cev[c] = 2.0 * dd / (36.0 * (double)K);
}

__global__ __launch_bounds__(256) void final_kernel(const double* __restrict__ ec_sum,
                                                    const double* __restrict__ cev,
                                                    float* __restrict__ loss_out) {
    const int tid = threadIdx.x;
    double s = 0.0;
    for (int i = tid; i < NMOD * NROWS; i += 256) s += cev[i];
    for (int i = tid; i < NMOD * DEPTH; i += 256) s += ec_sum[i] * (2.0 / (36.0 * (double)BATCH));
    #pragma unroll
    for (int o = 32; o > 0; o >>= 1) s += __shfl_xor(s, o);
    __shared__ double sw[4];
    if ((tid & 63) == 0) sw[tid >> 6] = s;
    __syncthreads();
    if (tid == 0) loss_out[0] = (float)(sw[0] + sw[1] + sw[2] + sw[3]);
}

extern "C" void kernel_launch(void* const* d_in, const int* in_sizes, int n_in,
                              void* d_out, int out_size, void* d_ws, size_t ws_size,
                              hipStream_t stream) {
    const float* latents = (const float*)d_in[0];
    const float* e0 = (const float*)d_in[1];
    const float* e1 = (const float*)d_in[2];
    const float* e2 = (const float*)d_in[3];
    const float* e3 = (const float*)d_in[4];
    const float* e4 = (const float*)d_in[5];
    const float* e5 = (const float*)d_in[6];

    float* out = (float*)d_out;
    float* tree_out = out;                                            // (6,8192,6)
    float* vec_out = out + (size_t)NMOD * BATCH * DEPTH;              // (6,8192,6,300)
    float* loss_out = vec_out + (size_t)NMOD * BATCH * DEPTH * EMB;   // scalar

    char* ws = (char*)d_ws;
    double* e_d = (double*)ws;                                        // 302400 B
    float* e_f = (float*)(ws + 302400);                               // 151200 B -> 453600
    unsigned long long* keys = (unsigned long long*)(ws + 453600);    // 6048 -> 459648
    unsigned long long* kpart = (unsigned long long*)(ws + 459648);   // 32*756*8 = 193536 -> 653184
    double* ecp = (double*)(ws + 653184);                             // 36*2048*8 = 589824 -> 1243008
    double* cev = (double*)(ws + 1243008);                            // 6048 -> 1249056
    double* ec_sum = (double*)(ws + 1249056);                         // 288 -> 1249344

    prep_kernel<<<dim3(NROWS + 1), dim3(64), 0, stream>>>(
        e0, e1, e2, e3, e4, e5, e_d, e_f, kpart);
    route_kernel<<<dim3(NMOD * BATCH / 4), dim3(256), 0, stream>>>(
        latents, e_d, e_f, tree_out, vec_out, kpart, ecp);
    reduce_kernel<<<dim3(NMOD * DEPTH + 3), dim3(256), 0, stream>>>(kpart, keys, ecp, ec_sum);
    ce_kernel<<<dim3((NMOD * NROWS + 3) / 4), dim3(256), 0, stream>>>(
        latents, e_d, keys, cev);
    final_kernel<<<dim3(1), dim3(256), 0, stream>>>(ec_sum, cev, loss_out);
}